// Round 8
// baseline (1942.678 us; speedup 1.0000x reference)
//
#include <hip/hip_runtime.h>
#include <hip/hip_bf16.h>
#include <math.h>

constexpr int B = 64, N = 307, F = 64, T = 12, K = 3, C = 64, CT = 64;
constexpr float LN_EPS = 1e-5f;
constexpr int FT = F * T;  // 768

typedef short sh8 __attribute__((ext_vector_type(8)));
typedef float f4 __attribute__((ext_vector_type(4)));
typedef __hip_bfloat16 hbf;

// ---------------- temporal attention ----------------

__global__ void k_lhs1_e(const float* __restrict__ x, const float* __restrict__ U1,
                         float* __restrict__ out) {
    int idx = blockIdx.x * blockDim.x + threadIdx.x;
    if (idx >= B * T * F) return;
    int f = idx % F;
    int t = (idx / F) % T;
    int b = idx / (F * T);
    const float* xp = x + ((size_t)b * N * F + f) * T + t;
    float s = 0.f;
    for (int n = 0; n < N; n++) s += xp[(size_t)n * F * T] * U1[n];
    out[idx] = s;
}

__global__ void k_xdots(const float* __restrict__ x, const float* __restrict__ U3,
                        const float* __restrict__ W3, float* __restrict__ rhs_e,
                        float* __restrict__ xw3) {
    int idx = blockIdx.x * blockDim.x + threadIdx.x;
    if (idx >= B * N * T) return;
    int t = idx % T;
    size_t bn = idx / T;
    const float* xp = x + bn * F * T + t;
    float s1 = 0.f, s2 = 0.f;
    for (int f = 0; f < F; f++) {
        float v = xp[f * T];
        s1 += U3[f] * v;
        s2 += W3[f] * v;
    }
    rhs_e[idx] = s1;
    xw3[idx] = s2;
}

__global__ void k_lhs_e(const float* __restrict__ lhs1, const float* __restrict__ U2,
                        float* __restrict__ out) {
    int idx = blockIdx.x * blockDim.x + threadIdx.x;
    if (idx >= B * T * N) return;
    int n = idx % N;
    int bt = idx / N;
    const float* lp = lhs1 + (size_t)bt * F;
    float s = 0.f;
    for (int f = 0; f < F; f++) s += lp[f] * U2[f * N + n];
    out[idx] = s;
}

__global__ void k_tatt(const float* __restrict__ lhs, const float* __restrict__ rhs,
                       const float* __restrict__ b_e, const float* __restrict__ V_e,
                       float* __restrict__ E) {
    int b = blockIdx.x;
    int tid = threadIdx.x;
    __shared__ float sig[T * T];
    __shared__ float Ev[T * T];
    __shared__ float mx[T], sm[T];
    if (tid < T * T) {
        int t = tid % T, u = tid / T;
        const float* lp = lhs + ((size_t)b * T + u) * N;
        const float* rp = rhs + (size_t)b * N * T + t;
        float s = 0.f;
        for (int n = 0; n < N; n++) s += lp[n] * rp[(size_t)n * T];
        s += b_e[u * T + t];
        sig[tid] = 1.f / (1.f + expf(-s));
    }
    __syncthreads();
    if (tid < T * T) {
        int t = tid % T, u = tid / T;
        float e = 0.f;
        for (int v = 0; v < T; v++) e += V_e[u * T + v] * sig[v * T + t];
        Ev[tid] = e;
    }
    __syncthreads();
    if (tid < T) {
        float m = -1e30f;
        for (int u = 0; u < T; u++) m = fmaxf(m, Ev[u * T + tid]);
        float s = 0.f;
        for (int u = 0; u < T; u++) s += expf(Ev[u * T + tid] - m);
        mx[tid] = m;
        sm[tid] = s;
    }
    __syncthreads();
    if (tid < T * T) {
        int t = tid % T;
        E[(size_t)b * T * T + tid] = expf(Ev[tid] - mx[t]) / sm[t];
    }
}

__global__ void k_EW1(const float* __restrict__ E, const float* __restrict__ W1,
                      float* __restrict__ out) {
    int idx = blockIdx.x * blockDim.x + threadIdx.x;
    if (idx >= B * T) return;
    const float* Ep = E + (size_t)idx * T;
    float s = 0.f;
    for (int t = 0; t < T; t++) s += Ep[t] * W1[t];
    out[idx] = s;
}

// ---------------- spatial attention ----------------

__global__ void k_lhs_sf(const float* __restrict__ x, const float* __restrict__ EW1,
                         const float* __restrict__ W2, float* __restrict__ lhs_s) {
    int bn = blockIdx.x;
    int b = bn / N;
    int tid = threadIdx.x;  // 64
    __shared__ float a[F];
    __shared__ float ew[T];
    if (tid < T) ew[tid] = EW1[(size_t)b * T + tid];
    __syncthreads();
    const float* xp = x + (size_t)bn * F * T + tid * T;
    float s = 0.f;
    for (int tp = 0; tp < T; tp++) s += xp[tp] * ew[tp];
    a[tid] = s;
    __syncthreads();
    if (tid < T) {
        float s2 = 0.f;
        for (int f = 0; f < F; f++) s2 += a[f] * W2[f * T + tid];
        lhs_s[(size_t)bn * T + tid] = s2;
    }
}

__global__ void k_rhs_s2(const float* __restrict__ xw3, const float* __restrict__ E,
                         float* __restrict__ out) {
    int idx = blockIdx.x * blockDim.x + threadIdx.x;
    if (idx >= B * T * N) return;
    int m = idx % N;
    int t = (idx / N) % T;
    int b = idx / (N * T);
    const float* xp = xw3 + ((size_t)b * N + m) * T;
    const float* Ep = E + (size_t)b * T * T + t;
    float s = 0.f;
    for (int tp = 0; tp < T; tp++) s += xp[tp] * Ep[tp * T];
    out[idx] = s;
}

__global__ void k_transposeVs(const float* __restrict__ V, float* __restrict__ VT) {
    int idx = blockIdx.x * blockDim.x + threadIdx.x;
    if (idx >= N * N) return;
    int v = idx % N;
    int i = idx / N;
    VT[(size_t)v * N + i] = V[(size_t)i * N + v];
}

__global__ void k_twT(const float* __restrict__ tw, float* __restrict__ twT) {
    int idx = blockIdx.x * blockDim.x + threadIdx.x;
    if (idx >= CT * C * 3) return;
    int dt = idx % 3;
    int c = (idx / 3) % C;
    int ct = idx / (3 * C);
    twT[((size_t)dt * CT + ct) * C + c] = tw[idx];
}

constexpr int AT = 4;
constexpr int NAB = (N + AT - 1) / AT;  // 77

__global__ void k_sigS(const float* __restrict__ lhs_s, const float* __restrict__ rhs_s,
                       const float* __restrict__ b_s, const float* __restrict__ VsT,
                       float* __restrict__ S) {
    int blk = blockIdx.x;
    int b = blk / NAB;
    int a0 = (blk % NAB) * AT;
    int tid = threadIdx.x;  // 256
    __shared__ float lrow[AT][T];
    __shared__ float sig4[AT][N];
    if (tid < AT * T) {
        int a = tid / T, t = tid % T;
        lrow[a][t] = (a0 + a < N) ? lhs_s[((size_t)b * N + a0 + a) * T + t] : 0.f;
    }
    __syncthreads();
    for (int v = tid; v < N; v += 256) {
        float rv[T];
        for (int t = 0; t < T; t++) rv[t] = rhs_s[((size_t)b * T + t) * N + v];
        for (int a = 0; a < AT; a++) {
            if (a0 + a >= N) break;
            float s = 0.f;
            for (int t = 0; t < T; t++) s += lrow[a][t] * rv[t];
            s += b_s[(size_t)(a0 + a) * N + v];
            sig4[a][v] = 1.f / (1.f + expf(-s));
        }
    }
    __syncthreads();
    for (int i = tid; i < N; i += 256) {
        float s[AT] = {0.f, 0.f, 0.f, 0.f};
        for (int v = 0; v < N; v++) {
            float vt = VsT[(size_t)v * N + i];
            for (int a = 0; a < AT; a++) s[a] += sig4[a][v] * vt;
        }
        for (int a = 0; a < AT; a++)
            if (a0 + a < N) S[((size_t)b * N + a0 + a) * N + i] = s[a];
    }
}

__global__ void k_softmax_S(float* __restrict__ S) {
    int idx = blockIdx.x * blockDim.x + threadIdx.x;
    if (idx >= B * N) return;
    int b = idx / N;
    int i = idx % N;
    float* p = S + (size_t)b * N * N + i;
    float m = -1e30f;
    for (int a = 0; a < N; a++) m = fmaxf(m, p[(size_t)a * N]);
    float s = 0.f;
    for (int a = 0; a < N; a++) s += expf(p[(size_t)a * N] - m);
    float inv = 1.f / s;
    for (int a = 0; a < N; a++) p[(size_t)a * N] = expf(p[(size_t)a * N] - m) * inv;
}

// ---------------- MFMA prep: W[b,k,j,i] bf16 (320x320 padded) ----------------
// W = (cheb_k .* S_b)^T ; rows j>=307 and cols i>=307 zero.
__global__ void k_mkW(const float* __restrict__ cheb, const float* __restrict__ S,
                      hbf* __restrict__ W) {
    int blk = blockIdx.x;
    int bk = blk / 25;          // b*3+k
    int b = bk / 3, k = bk % 3;
    int tp = blk % 25;
    int it = tp / 5, jt = tp % 5;
    int tid = threadIdx.x;
    __shared__ float tile[64][65];
    for (int l = tid; l < 64 * 64; l += 256) {
        int ii = l >> 6, jj = l & 63;
        int i = it * 64 + ii, jx = jt * 64 + jj;
        float v = 0.f;
        if (i < N && jx < N)
            v = cheb[((size_t)k * N + i) * N + jx] * S[((size_t)b * N + i) * N + jx];
        tile[ii][jj] = v;
    }
    __syncthreads();
    for (int l = tid; l < 64 * 64; l += 256) {
        int jj = l >> 6, ii = l & 63;
        W[((size_t)bk * 320 + jt * 64 + jj) * 320 + it * 64 + ii] =
            __float2bfloat16(tile[ii][jj]);
    }
}

// ---------------- MFMA prep: Xt[b,e,i] bf16 (768 x 320 padded) ----------------
__global__ void k_mkXt(const float* __restrict__ x, hbf* __restrict__ Xt) {
    int blk = blockIdx.x;
    int b = blk / 60;
    int tp = blk % 60;
    int it = tp / 12, et = tp % 12;
    int tid = threadIdx.x;
    __shared__ float tile[64][65];
    for (int l = tid; l < 64 * 64; l += 256) {
        int ii = l >> 6, ee = l & 63;
        int i = it * 64 + ii;
        tile[ii][ee] = (i < N) ? x[((size_t)b * N + i) * FT + et * 64 + ee] : 0.f;
    }
    __syncthreads();
    for (int l = tid; l < 64 * 64; l += 256) {
        int ee = l >> 6, ii = l & 63;
        Xt[((size_t)b * 768 + et * 64 + ee) * 320 + it * 64 + ii] =
            __float2bfloat16(tile[ii][ee]);
    }
}

// ---------------- MFMA graph conv + Theta + relu -> sg (d_out) ----------------
// Block: (b, 16-j tile). 4 waves; wave w owns e-tiles [w*12, w*12+12), all 3 k.
// A[m=lane&15][kk=quad*8+jj] from W rows; B symmetric from Xt rows;
// C/D: col=lane&15 (e), row=quad*4+reg (j).  [guide-verified mappings]
__global__ void k_gcnz_mfma(const hbf* __restrict__ Wbf, const hbf* __restrict__ Xt,
                            const float* __restrict__ Theta, float* __restrict__ sg) {
    int blk = blockIdx.x;
    int b = blk / 20;
    int j0 = (blk % 20) * 16;
    int tid = threadIdx.x;  // 256
    int wv = tid >> 6;
    int lane = tid & 63;
    int q = lane >> 4;
    int n = lane & 15;
    int et0 = wv * 12;

    __shared__ hbf zl[768][16];  // 24 KB, one k at a time

    f4 acc[K][12];
#pragma unroll
    for (int k = 0; k < K; k++)
#pragma unroll
        for (int e = 0; e < 12; e++) {
            f4 z = {0.f, 0.f, 0.f, 0.f};
            acc[k][e] = z;
        }

    const hbf* Wb = Wbf + (size_t)b * (3 * 320 * 320);
    const hbf* Xb = Xt + (size_t)b * (768 * 320);

    for (int i0 = 0; i0 < 320; i0 += 32) {
        sh8 af[K];
#pragma unroll
        for (int k = 0; k < K; k++)
            af[k] = *(const sh8*)(Wb + ((size_t)k * 320 + j0 + n) * 320 + i0 + q * 8);
#pragma unroll
        for (int e = 0; e < 12; e++) {
            sh8 bfr = *(const sh8*)(Xb + ((size_t)(et0 + e) * 16 + n) * 320 + i0 + q * 8);
#pragma unroll
            for (int k = 0; k < K; k++)
                acc[k][e] = __builtin_amdgcn_mfma_f32_16x16x32_bf16(af[k], bfr, acc[k][e], 0, 0, 0);
        }
    }

    // Theta contraction, one k-pass at a time through LDS
    float o[64];
#pragma unroll
    for (int c = 0; c < 64; c++) o[c] = 0.f;
    int j = tid / 12, t = tid % 12;  // valid when tid<192

    for (int k = 0; k < K; k++) {
#pragma unroll
        for (int e = 0; e < 12; e++) {
            int eg = (et0 + e) * 16 + n;
#pragma unroll
            for (int r = 0; r < 4; r++)
                zl[eg][q * 4 + r] = __float2bfloat16(acc[k][e][r]);
        }
        __syncthreads();
        if (tid < 192) {
            const float* thk = Theta + (size_t)k * F * C;
            for (int f = 0; f < F; f++) {
                float zv = __bfloat162float(zl[f * 12 + t][j]);
                const float* th = thk + f * C;  // wave-uniform -> s_load
#pragma unroll
                for (int c = 0; c < 64; c++) o[c] += zv * th[c];
            }
        }
        __syncthreads();
    }

    if (tid < 192) {
        int jg = j0 + j;
        if (jg < N) {
            float* op = sg + ((size_t)b * N + jg) * FT;
#pragma unroll
            for (int c = 0; c < 64; c++) op[c * 12 + t] = fmaxf(o[c], 0.f);
        }
    }
}

// ---------------- fallback VALU graph conv (r7 version, proven) ----------------
constexpr int JT = 4;
constexpr int NJB = (N + JT - 1) / JT;  // 77

__global__ void k_gcnz(const float* __restrict__ x, const float* __restrict__ S,
                       const float* __restrict__ cheb, const float* __restrict__ Theta,
                       float* __restrict__ sg) {
    int blk = blockIdx.x;
    int b = blk / NJB;
    int j0 = (blk % NJB) * JT;
    int tid = threadIdx.x;

    __shared__ float wl[64][K * JT];
    __shared__ float zl[K][JT][FT];

    float acc[K][JT][3];
#pragma unroll
    for (int k = 0; k < K; k++)
#pragma unroll
        for (int jj = 0; jj < JT; jj++)
#pragma unroll
            for (int r = 0; r < 3; r++) acc[k][jj][r] = 0.f;

    const float* xb = x + (size_t)b * N * FT;

    for (int ic = 0; ic < N; ic += 64) {
        for (int l = tid; l < 64 * K * JT; l += 256) {
            int ii = l / (K * JT);
            int m = l % (K * JT);
            int k = m / JT, jj = m % JT;
            int i = ic + ii, j = j0 + jj;
            float w = 0.f;
            if (i < N && j < N)
                w = cheb[((size_t)k * N + i) * N + j] * S[((size_t)b * N + i) * N + j];
            wl[ii][m] = w;
        }
        __syncthreads();
        int imax = min(64, N - ic);
        for (int ii = 0; ii < imax; ii++) {
            float xv[3];
            const float* xr = xb + (size_t)(ic + ii) * FT;
#pragma unroll
            for (int r = 0; r < 3; r++) xv[r] = xr[tid + 256 * r];
#pragma unroll
            for (int k = 0; k < K; k++)
#pragma unroll
                for (int jj = 0; jj < JT; jj++) {
                    float w = wl[ii][k * JT + jj];
#pragma unroll
                    for (int r = 0; r < 3; r++) acc[k][jj][r] += w * xv[r];
                }
        }
        __syncthreads();
    }

#pragma unroll
    for (int k = 0; k < K; k++)
#pragma unroll
        for (int jj = 0; jj < JT; jj++)
#pragma unroll
            for (int r = 0; r < 3; r++) zl[k][jj][tid + 256 * r] = acc[k][jj][r];
    __syncthreads();

    for (int r = 0; r < 3; r++) {
        int e = tid + 256 * r;
        int c = e / T;
        int t = e % T;
        float s[JT] = {0.f, 0.f, 0.f, 0.f};
        for (int k = 0; k < K; k++) {
            const float* tp = Theta + (size_t)k * F * C + c;
            const float* zp = &zl[k][0][t];
#pragma unroll 4
            for (int f = 0; f < F; f++) {
                float tv = tp[f * C];
#pragma unroll
                for (int jj = 0; jj < JT; jj++) s[jj] += zp[jj * FT + f * T] * tv;
            }
        }
#pragma unroll
        for (int jj = 0; jj < JT; jj++) {
            int j = j0 + jj;
            if (j < N) sg[((size_t)b * N + j) * FT + e] = fmaxf(s[jj], 0.f);
        }
    }
}

// ---------------- tconv + rconv + relu + LayerNorm (in-place on d_out) ----------------
constexpr int RB = 4;
constexpr int PF = 68;

__global__ void k_rest(const float* __restrict__ x, const float* __restrict__ twT,
                       const float* __restrict__ tb, const float* __restrict__ rw,
                       const float* __restrict__ rb, const float* __restrict__ gamma,
                       const float* __restrict__ beta, float* __restrict__ io) {
    int blk = blockIdx.x;
    size_t bn0 = (size_t)blk * RB;
    int tid = threadIdx.x;

    __shared__ float xt[RB][T][PF];
    __shared__ float sgt[RB][T + 2][PF];
    __shared__ float hl[FT];
    __shared__ float mus[T], rstds[T];

    for (int l = tid; l < RB * PF; l += 256) {
        int rr = l / PF, c = l % PF;
        sgt[rr][0][c] = 0.f;
        sgt[rr][T + 1][c] = 0.f;
    }
    for (int l = tid; l < RB * FT; l += 256) {
        int rr = l / FT, rem = l % FT;
        int f = rem / T, t = rem % T;
        xt[rr][t][f] = x[(bn0 + rr) * FT + rem];
        sgt[rr][t + 1][f] = io[(bn0 + rr) * FT + rem];
    }
    __syncthreads();

    for (int rr = 0; rr < RB; rr++) {
        float hreg[3];
#pragma unroll
        for (int r = 0; r < 3; r++) {
            int e = tid + 256 * r;
            int ct = e / T;
            int t = e % T;
            float acc = rb[ct] + tb[ct];
            const float4* rwp = (const float4*)(rw + (size_t)ct * F);
            const float4* xp4 = (const float4*)(&xt[rr][t][0]);
#pragma unroll 4
            for (int qq = 0; qq < F / 4; qq++) {
                float4 w = rwp[qq], v = xp4[qq];
                acc += w.x * v.x + w.y * v.y + w.z * v.z + w.w * v.w;
            }
#pragma unroll
            for (int dt = 0; dt < 3; dt++) {
                const float4* twp = (const float4*)(twT + ((size_t)dt * CT + ct) * C);
                const float4* sp4 = (const float4*)(&sgt[rr][t + dt][0]);
#pragma unroll 4
                for (int qq = 0; qq < C / 4; qq++) {
                    float4 w = twp[qq], v = sp4[qq];
                    acc += w.x * v.x + w.y * v.y + w.z * v.z + w.w * v.w;
                }
            }
            hreg[r] = fmaxf(acc, 0.f);
            hl[e] = hreg[r];
        }
        __syncthreads();
        if (tid < T) {
            float m = 0.f;
            for (int ct = 0; ct < CT; ct++) m += hl[ct * T + tid];
            m /= CT;
            float v = 0.f;
            for (int ct = 0; ct < CT; ct++) {
                float d = hl[ct * T + tid] - m;
                v += d * d;
            }
            v /= CT;
            mus[tid] = m;
            rstds[tid] = rsqrtf(v + LN_EPS);
        }
        __syncthreads();
        float* iop = io + (bn0 + rr) * FT;
#pragma unroll
        for (int r = 0; r < 3; r++) {
            int e = tid + 256 * r;
            int ct = e / T;
            int t = e % T;
            iop[e] = (hreg[r] - mus[t]) * rstds[t] * gamma[ct] + beta[ct];
        }
        __syncthreads();
    }
}

// ---------------- launch ----------------

extern "C" void kernel_launch(void* const* d_in, const int* in_sizes, int n_in,
                              void* d_out, int out_size, void* d_ws, size_t ws_size,
                              hipStream_t stream) {
    const float* x     = (const float*)d_in[0];
    const float* W1    = (const float*)d_in[1];
    const float* W2    = (const float*)d_in[2];
    const float* W3    = (const float*)d_in[3];
    const float* b_s   = (const float*)d_in[4];
    const float* V_s   = (const float*)d_in[5];
    const float* U1    = (const float*)d_in[6];
    const float* U2    = (const float*)d_in[7];
    const float* U3    = (const float*)d_in[8];
    const float* b_e   = (const float*)d_in[9];
    const float* V_e   = (const float*)d_in[10];
    const float* cheb  = (const float*)d_in[11];
    const float* Theta = (const float*)d_in[12];
    const float* tw    = (const float*)d_in[13];
    const float* tb    = (const float*)d_in[14];
    const float* rw    = (const float*)d_in[15];
    const float* rb    = (const float*)d_in[16];
    const float* gam   = (const float*)d_in[17];
    const float* bet   = (const float*)d_in[18];
    float* out = (float*)d_out;

    float* ws = (float*)d_ws;
    size_t off = 0;
    auto alloc = [&](size_t n) { float* p = ws + off; off += n; return p; };
    float* Sb     = alloc((size_t)B * N * N);
    float* VsT    = alloc((size_t)N * N);
    float* twT    = alloc((size_t)CT * C * 3);
    float* lhs1_e = alloc((size_t)B * T * F);
    float* lhs_e  = alloc((size_t)B * T * N);
    float* rhs_e  = alloc((size_t)B * N * T);
    float* Ebuf   = alloc((size_t)B * T * T);
    float* EW1    = alloc((size_t)B * T);
    float* xw3    = alloc((size_t)B * N * T);
    float* lhs_s  = alloc((size_t)B * N * T);
    float* rhs_s  = alloc((size_t)B * T * N);

    // bf16 MFMA operand buffers (appended; checked against ws_size)
    size_t base_bytes = off * sizeof(float);
    size_t w_el  = (size_t)B * 3 * 320 * 320;
    size_t xt_el = (size_t)B * 768 * 320;
    size_t mfma_bytes = base_bytes + (w_el + xt_el) * sizeof(hbf);
    bool use_mfma = (ws_size >= mfma_bytes);
    hbf* Wbf = (hbf*)(ws + off);
    hbf* Xtb = Wbf + w_el;

    auto g = [](long n) { return dim3((unsigned)((n + 255) / 256)); };

    // temporal attention
    k_lhs1_e<<<g((long)B * T * F), 256, 0, stream>>>(x, U1, lhs1_e);
    k_xdots<<<g((long)B * N * T), 256, 0, stream>>>(x, U3, W3, rhs_e, xw3);
    k_lhs_e<<<g((long)B * T * N), 256, 0, stream>>>(lhs1_e, U2, lhs_e);
    k_tatt<<<B, 256, 0, stream>>>(lhs_e, rhs_e, b_e, V_e, Ebuf);

    // spatial attention
    k_EW1<<<g((long)B * T), 256, 0, stream>>>(Ebuf, W1, EW1);
    k_lhs_sf<<<B * N, 64, 0, stream>>>(x, EW1, W2, lhs_s);
    k_rhs_s2<<<g((long)B * T * N), 256, 0, stream>>>(xw3, Ebuf, rhs_s);
    k_transposeVs<<<g((long)N * N), 256, 0, stream>>>(V_s, VsT);
    k_twT<<<g((long)CT * C * 3), 256, 0, stream>>>(tw, twT);
    k_sigS<<<B * NAB, 256, 0, stream>>>(lhs_s, rhs_s, b_s, VsT, Sb);
    k_softmax_S<<<g((long)B * N), 256, 0, stream>>>(Sb);

    if (use_mfma) {
        k_mkXt<<<B * 60, 256, 0, stream>>>(x, Xtb);
        k_mkW<<<B * 3 * 25, 256, 0, stream>>>(cheb, Sb, Wbf);
        k_gcnz_mfma<<<B * 20, 256, 0, stream>>>(Wbf, Xtb, Theta, out);
    } else {
        k_gcnz<<<B * NJB, 256, 0, stream>>>(x, Sb, cheb, Theta, out);
    }

    // tconv + rconv + relu + LN, in-place on d_out
    k_rest<<<(B * N) / RB, 256, 0, stream>>>(x, twT, tb, rw, rb, gam, bet, out);
}